// Round 2
// baseline (367.944 us; speedup 1.0000x reference)
//
#include <hip/hip_runtime.h>

// B=16, Q=2048, K=2048, D=128, DV=128
// out[b,q,:] = softmax_k((q.k - 0.5||k||^2)/sqrt(192), mask k>=valid_len) @ V
// R10: occupancy attack. R9 showed all pipes <=35% at 2 waves/SIMD (LDS-capped
// 2 blocks/CU). Changes:
//  - V tile single-buffered (V fragments prefetched to registers before the
//    mid-body barrier) -> LDS 66.5KB -> 49KB -> 3 blocks/CU.
//  - K split in halves across blocks (grid 1024, 16 K-tiles each) so the
//    3rd block slot is actually fillable. Halves merged by arrival order:
//    first-arriver stages raw partial O in Og + psums in ws, fence, flag;
//    second-arriver (partner provably running -> spin is deadlock-free)
//    reads partner partial, adds its own (still in regs), normalizes.
//  - prep_kv: tmp[32] local array removed (alloca->scratch suspect for the
//    ~84us of dur_us not attributable to attn).

#define Bn   16
#define Qn   2048
#define Kn   2048
#define Dn   128
#define DVn  128
#define BQ   64
#define BK   64
#define KH   1024    // keys per block (split-K half)
#define NT   16      // K-tiles per block

// (1/sqrt(192)) * log2(e) : softmax computed as 2^(qk*SC2 + bias2)
#define SC2 0.10411754f

typedef short bf16x4 __attribute__((ext_vector_type(4)));
typedef short bf16x8 __attribute__((ext_vector_type(8)));
typedef float f32x16 __attribute__((ext_vector_type(16)));

__device__ __forceinline__ short f2bf(float x) {   // RNE
    union { float f; unsigned u; } v; v.f = x;
    unsigned r = (v.u + 0x7fffu + ((v.u >> 16) & 1u)) >> 16;
    return (short)r;
}

typedef const __attribute__((address_space(1))) void* gas_t;
typedef __attribute__((address_space(3))) void* las_t;
__device__ __forceinline__ void gld16(const void* g, void* l) {
    __builtin_amdgcn_global_load_lds((gas_t)g, (las_t)l, 16, 0, 0);
}
__device__ __forceinline__ void gld4(const void* g, void* l) {
    __builtin_amdgcn_global_load_lds((gas_t)g, (las_t)l, 4, 0, 0);
}
__device__ __forceinline__ float exp2_raw(float a) {  // D = 2^S0
    float p;
    asm("v_exp_f32 %0, %1" : "=v"(p) : "v"(a));
    return p;
}

// ---------- preprocess ----------
__global__ __launch_bounds__(256) void prep_kv(const float* __restrict__ Kg,
                                               const float* __restrict__ Vg,
                                               short* __restrict__ Kb,
                                               short* __restrict__ Vtb,
                                               float* __restrict__ biasg,
                                               int* __restrict__ flags) {
    __shared__ short Ls[64 * 128];
    const int tid = threadIdx.x;
    if (blockIdx.x < 512) {
        if (blockIdx.x == 0) {   // zero merge flags (1024 ints) each rep
            flags[tid] = 0; flags[tid + 256] = 0;
            flags[tid + 512] = 0; flags[tid + 768] = 0;
        }
        const int b  = blockIdx.x >> 5;
        const int k0 = (blockIdx.x & 31) * 64;
        const int row = k0 + (tid >> 2);
        const int c   = (tid & 3) * 32;
        const float* src = Kg + ((size_t)b * Kn + row) * Dn + c;
        short*       dst = Kb + ((size_t)b * Kn + row) * Dn + c;
        float ssq = 0.f;
#pragma unroll
        for (int j = 0; j < 4; ++j) {
            float4 x0 = *(const float4*)(src + j * 8);
            float4 x1 = *(const float4*)(src + j * 8 + 4);
            ssq += x0.x*x0.x + x0.y*x0.y + x0.z*x0.z + x0.w*x0.w
                 + x1.x*x1.x + x1.y*x1.y + x1.z*x1.z + x1.w*x1.w;
            bf16x8 h;
            h[0]=f2bf(x0.x); h[1]=f2bf(x0.y); h[2]=f2bf(x0.z); h[3]=f2bf(x0.w);
            h[4]=f2bf(x1.x); h[5]=f2bf(x1.y); h[6]=f2bf(x1.z); h[7]=f2bf(x1.w);
            *(bf16x8*)(dst + j * 8) = h;
        }
        ssq += __shfl_xor(ssq, 1);
        ssq += __shfl_xor(ssq, 2);
        if ((tid & 3) == 0) biasg[b * Kn + row] = -0.5f * ssq * SC2;
    } else {
        const int blk = blockIdx.x - 512;
        const int b  = blk >> 5;
        const int k0 = (blk & 31) * 64;
        {
            const int key = tid >> 2;
            const float* src = Vg + ((size_t)b * Kn + k0 + key) * DVn + (tid & 3) * 32;
#pragma unroll
            for (int cj = 0; cj < 4; ++cj) {
                float4 x0 = *(const float4*)(src + cj * 8);
                float4 x1 = *(const float4*)(src + cj * 8 + 4);
                bf16x8 h;
                h[0]=f2bf(x0.x); h[1]=f2bf(x0.y); h[2]=f2bf(x0.z); h[3]=f2bf(x0.w);
                h[4]=f2bf(x1.x); h[5]=f2bf(x1.y); h[6]=f2bf(x1.z); h[7]=f2bf(x1.w);
                const int ch = (tid & 3) * 4 + cj;
                const int sw = (ch + key) & 15;
                *(bf16x8*)&Ls[key * 128 + sw * 8] = h;
            }
        }
        __syncthreads();
        {
            const int v = tid >> 1;
            const int h = (tid & 1) * 32;
            short* dst = Vtb + ((size_t)b * DVn + v) * Kn + k0 + h;
#pragma unroll
            for (int j4 = 0; j4 < 4; ++j4) {
                bf16x8 o;
#pragma unroll
                for (int j = 0; j < 8; ++j) {
                    const int kk = h + j4 * 8 + j;
                    const int sw = ((v >> 3) + kk) & 15;
                    o[j] = Ls[kk * 128 + sw * 8 + (v & 7)];
                }
                *(bf16x8*)(dst + j4 * 8) = o;
            }
        }
    }
}

// ---- epilogue helpers (literal accumulator indices only) ----
#define DUMP_ACC(ACC, DST)                                            \
    {                                                                 \
        _Pragma("unroll")                                             \
        for (int reg = 0; reg < 16; ++reg) {                          \
            const int row = (reg & 3) + 8 * (reg >> 2) + 4 * hi;      \
            (DST)[row * 32 + l31] = (ACC)[reg];                       \
        }                                                             \
    }
#define STORE_RAW(ACC, SRC, COLBASE)                                  \
    {                                                                 \
        _Pragma("unroll")                                             \
        for (int reg = 0; reg < 16; ++reg) {                          \
            const int row = (reg & 3) + 8 * (reg >> 2) + 4 * hi;      \
            obase[(size_t)row * DVn + (COLBASE) + l31] =              \
                (ACC)[reg] + (SRC)[row * 32 + l31];                   \
        }                                                             \
    }
#define STORE_MRG(ACC, SRC, COLBASE)                                  \
    {                                                                 \
        _Pragma("unroll")                                             \
        for (int reg = 0; reg < 16; ++reg) {                          \
            const int row = (reg & 3) + 8 * (reg >> 2) + 4 * hi;      \
            const float o = (ACC)[reg] + (SRC)[row * 32 + l31]        \
                + obase[(size_t)row * DVn + (COLBASE) + l31];         \
            obase[(size_t)row * DVn + (COLBASE) + l31] = o * invl[reg]; \
        }                                                             \
    }

// ---- main-loop building blocks ----

// S tile I: one 32x32 score tile per wave from Ksh[(I)&1] (8 MFMA)
#define S_COMPUTE(I)                                                       \
    {                                                                      \
        const short* kbuf = Ksh[(I) & 1];                                  \
        _Pragma("unroll")                                                  \
        for (int j = 0; j < 16; ++j) Sv[j] = 0.f;                          \
        __builtin_amdgcn_s_setprio(1);                                     \
        _Pragma("unroll")                                                  \
        for (int kt = 0; kt < 8; ++kt) {                                   \
            bf16x8 kf = *(const bf16x8*)&kbuf[kr * 128 + (((kt*2 + hi) ^ (kr & 15)) * 8)]; \
            Sv = __builtin_amdgcn_mfma_f32_32x32x16_bf16(kf, qf[kt], Sv, 0, 0, 0); \
        }                                                                  \
        __builtin_amdgcn_s_setprio(0);                                     \
    }

// prefetch the 8 V fragments of the CURRENT Vsh content into registers
#define VPREF                                                              \
    {                                                                      \
        vfA0 = *(const bf16x8*)&Vsh[vbaseA + 0 * 2048];                    \
        vfA1 = *(const bf16x8*)&Vsh[vbaseA + 1 * 2048];                    \
        vfA2 = *(const bf16x8*)&Vsh[vbaseA + 2 * 2048];                    \
        vfA3 = *(const bf16x8*)&Vsh[vbaseA + 3 * 2048];                    \
        vfB0 = *(const bf16x8*)&Vsh[vbaseB + 0 * 2048];                    \
        vfB1 = *(const bf16x8*)&Vsh[vbaseB + 1 * 2048];                    \
        vfB2 = *(const bf16x8*)&Vsh[vbaseB + 2 * 2048];                    \
        vfB3 = *(const bf16x8*)&Vsh[vbaseB + 3 * 2048];                    \
    }

// softmax tile J (in Sv) + pack into aA,aB
#define SOFTPACK(J)                                                        \
    {                                                                      \
        const int jj = (J);                                                \
        const int jb = jj & 1;                                             \
        float4 bv[4];                                                      \
        _Pragma("unroll")                                                  \
        for (int rq = 0; rq < 4; ++rq)                                     \
            bv[rq] = *(const float4*)&biasSh[jb][half * 32 + rq * 8 + hi * 4]; \
        _Pragma("unroll")                                                  \
        for (int rq = 0; rq < 4; ++rq) {                                   \
            _Pragma("unroll")                                              \
            for (int r = 0; r < 4; ++r) {                                  \
                const int reg = rq * 4 + r;                                \
                const int keyg = kbase + jj * BK + half * 32 + rq * 8 + hi * 4 + r; \
                float a = fmaf(Sv[reg], SC2, bv[rq][r]);                   \
                a = (keyg < vlq) ? a : -200.0f;                            \
                const float p = exp2_raw(a);                               \
                psum += p;                                                 \
                Sv[reg] = p;                                               \
            }                                                              \
        }                                                                  \
        _Pragma("unroll")                                                  \
        for (int kt = 0; kt < 2; ++kt) {                                   \
            unsigned kAx = __builtin_amdgcn_perm(__float_as_uint(Sv[(2*kt)*4+1]),   \
                                                 __float_as_uint(Sv[(2*kt)*4+0]), 0x07060302u); \
            unsigned kAy = __builtin_amdgcn_perm(__float_as_uint(Sv[(2*kt)*4+3]),   \
                                                 __float_as_uint(Sv[(2*kt)*4+2]), 0x07060302u); \
            unsigned kBx = __builtin_amdgcn_perm(__float_as_uint(Sv[(2*kt+1)*4+1]), \
                                                 __float_as_uint(Sv[(2*kt+1)*4+0]), 0x07060302u); \
            unsigned kBy = __builtin_amdgcn_perm(__float_as_uint(Sv[(2*kt+1)*4+3]), \
                                                 __float_as_uint(Sv[(2*kt+1)*4+2]), 0x07060302u); \
            const unsigned sx = hi ? kAx : kBx;                            \
            const unsigned sy = hi ? kAy : kBy;                            \
            const unsigned rx = __shfl_xor(sx, 32);                        \
            const unsigned ry = __shfl_xor(sy, 32);                        \
            uint4 au;                                                      \
            au.x = hi ? rx : kAx;                                          \
            au.y = hi ? ry : kAy;                                          \
            au.z = hi ? kBx : rx;                                          \
            au.w = hi ? kBy : ry;                                          \
            const bf16x8 af = __builtin_bit_cast(bf16x8, au);              \
            if (kt == 0) aA = af; else aB = af;                            \
        }                                                                  \
    }

#define PVMM                                                               \
    {                                                                      \
        __builtin_amdgcn_s_setprio(1);                                     \
        Oacc[0] = __builtin_amdgcn_mfma_f32_32x32x16_bf16(aA, vfA0, Oacc[0], 0, 0, 0); \
        Oacc[1] = __builtin_amdgcn_mfma_f32_32x32x16_bf16(aA, vfA1, Oacc[1], 0, 0, 0); \
        Oacc[2] = __builtin_amdgcn_mfma_f32_32x32x16_bf16(aA, vfA2, Oacc[2], 0, 0, 0); \
        Oacc[3] = __builtin_amdgcn_mfma_f32_32x32x16_bf16(aA, vfA3, Oacc[3], 0, 0, 0); \
        Oacc[0] = __builtin_amdgcn_mfma_f32_32x32x16_bf16(aB, vfB0, Oacc[0], 0, 0, 0); \
        Oacc[1] = __builtin_amdgcn_mfma_f32_32x32x16_bf16(aB, vfB1, Oacc[1], 0, 0, 0); \
        Oacc[2] = __builtin_amdgcn_mfma_f32_32x32x16_bf16(aB, vfB2, Oacc[2], 0, 0, 0); \
        Oacc[3] = __builtin_amdgcn_mfma_f32_32x32x16_bf16(aB, vfB3, Oacc[3], 0, 0, 0); \
        __builtin_amdgcn_s_setprio(0);                                     \
    }

// one body: issue K_{I+1}; prefetch V_{I-1} frags; softmax(I-1); barrier;
// issue V_I+bias_I; PV(I-1); S(I); barrier.
#define BODY2(I, DOK)                                                      \
    {                                                                      \
        if (DOK) {                                                         \
            const size_t ko = (size_t)((I) + 1) * BK * Dn;                 \
            _Pragma("unroll")                                              \
            for (int u = 0; u < 4; ++u)                                    \
                gld16(ksp[u] + ko, &Ksh[((I) + 1) & 1][kdo[u]]);           \
        }                                                                  \
        VPREF;                                                             \
        SOFTPACK((I) - 1);                                                 \
        __syncthreads();   /* K_{I+1} drained; all Vsh/Ksh reads done */   \
        {                                                                  \
            const int vo = (I) * BK;                                       \
            _Pragma("unroll")                                              \
            for (int u = 0; u < 4; ++u)                                    \
                gld16(vsp[u] + vo, &Vsh[vdo[u]]);                          \
            if (w == 0) gld4(bias_b + vo + lane, &biasSh[(I) & 1][0]);     \
        }                                                                  \
        PVMM;                                                              \
        S_COMPUTE((I));                                                    \
        __syncthreads();   /* V_I/bias_I drained; Ksh[I&1] reads done */   \
    }

// ---------- main attention kernel (split-K halves) ----------
__global__ __launch_bounds__(256, 3) void attn_kernel(
    const float* __restrict__ Qg, const short* __restrict__ Kb,
    const short* __restrict__ Vtb, const float* __restrict__ biasg,
    const int* __restrict__ VL, float* __restrict__ Og,
    float* __restrict__ psums, int* __restrict__ flags)
{
    __shared__ __align__(16) short Ksh[2][64 * 128];   // 32768 B (epilogue: float slab)
    __shared__ __align__(16) short Vsh[64 * 128];      // 16384 B (single buffer)
    __shared__ __align__(16) float biasSh[2][64];      //   512 B
    __shared__ float Lsum[4][32];                      //   512 B
    __shared__ int   roleSh;                           // ~49 KB total -> 3 blocks/CU

    const int tid  = threadIdx.x;
    const int lane = tid & 63;
    const int w    = tid >> 6;    // wave 0..3
    const int pair = w >> 1;      // q-strip: rows [pair*32, pair*32+32)
    const int half = w & 1;       // key-half within 64-key tile (wave-uniform)
    const int l31  = lane & 31;
    const int hi   = lane >> 5;

    // grid 1024: XCD-contiguous job mapping
    const int lin   = blockIdx.x;
    const int job   = (lin & 7) * 128 + (lin >> 3);
    const int panel = job >> 5;           // 0..31 = b*2 + khalf
    const int qslot = job & 31;
    const int b     = panel >> 1;
    const int khalf = panel & 1;
    const int q0    = qslot * BQ;
    const int kbase = khalf * KH;
    const int fid   = b * 32 + qslot;     // merge-pair id
    int* flagA = flags;
    int* flagB = flags + 512;

    const short* Kb_b = Kb  + ((size_t)b * Kn + kbase) * Dn;
    const short* Vt_b = Vtb + (size_t)b * DVn * Kn;
    const float* bias_b = biasg + b * Kn + kbase;

    // ---- DMA source pointers ----
    const short* ksp[4]; int kdo[4];
    const short* vsp[4]; int vdo[4];
#pragma unroll
    for (int i = 0; i < 4; ++i) {
        const int rl = w * 16 + i * 4 + (lane >> 4);       // tile row 0..63
        const int ch = (lane & 15) ^ (rl & 15);
        ksp[i] = Kb_b + (size_t)rl * Dn + ch * 8;
        kdo[i] = (w * 16 + i * 4) * 128;
        const int rv = rl;
        const int cc = (lane & 15) ^ (rv & 15);            // source chunk
        const int vv = 2 * rv + (cc >> 3);
        vsp[i] = Vt_b + (size_t)vv * Kn + kbase + (cc & 7) * 8;
        vdo[i] = (w * 16 + i * 4) * 128;
    }

    // ---- Q fragments ----
    bf16x8 qf[8];
    {
        const float* qrow = Qg + ((size_t)b * Qn + q0 + pair * 32 + l31) * Dn;
#pragma unroll
        for (int kt = 0; kt < 8; ++kt) {
            const float* p = qrow + kt * 16 + hi * 8;
            float4 x0 = *(const float4*)(p);
            float4 x1 = *(const float4*)(p + 4);
            bf16x8 f;
            f[0]=f2bf(x0.x); f[1]=f2bf(x0.y); f[2]=f2bf(x0.z); f[3]=f2bf(x0.w);
            f[4]=f2bf(x1.x); f[5]=f2bf(x1.y); f[6]=f2bf(x1.z); f[7]=f2bf(x1.w);
            qf[kt] = f;
        }
    }
    const int vlq = VL[b * Qn + q0 + pair * 32 + l31];
    const int kr  = half * 32 + l31;

    // V-fragment LDS base offsets (nt stride is 2048 shorts)
    const int l2h = l31 >> 1;
    const int s8  = (l31 & 1) * 8;
    const int vbaseA = l2h * 128 + ((s8 + half * 4 + 0 + hi) ^ l2h) * 8;
    const int vbaseB = l2h * 128 + ((s8 + half * 4 + 2 + hi) ^ l2h) * 8;

    f32x16 Oacc[4];
#pragma unroll
    for (int nt = 0; nt < 4; ++nt)
#pragma unroll
        for (int j = 0; j < 16; ++j) Oacc[nt][j] = 0.f;
    float psum = 0.f;
    f32x16 Sv;
    bf16x8 vfA0, vfA1, vfA2, vfA3, vfB0, vfB1, vfB2, vfB3, aA, aB;

    // prologue: stage K_0, K_1, V_0, bias_0
#pragma unroll
    for (int i = 0; i < 4; ++i) {
        gld16(ksp[i], &Ksh[0][kdo[i]]);
        gld16(ksp[i] + (size_t)BK * Dn, &Ksh[1][kdo[i]]);
        gld16(vsp[i], &Vsh[vdo[i]]);
    }
    if (w == 0) gld4(bias_b + lane, &biasSh[0][0]);
    __syncthreads();
    S_COMPUTE(0);
    __syncthreads();

#pragma unroll 1
    for (int I = 1; I < NT; ++I) {
        BODY2(I, (I < NT - 1));
    }
    // tail: finish tile NT-1
    VPREF;
    SOFTPACK(NT - 1);
    PVMM;

    // ---- epilogue: combine key-halves across wave pairs via LDS ----
    psum += __shfl_xor(psum, 32);
    if (lane < 32) Lsum[w][l31] = psum;
    __syncthreads();   // all waves done with Ksh/Vsh -> safe to reuse Ksh

    float* slab = (float*)&Ksh[0][0];
    {
        float* dst0 = slab + ((pair * 2 + (1 - half)) * 2 + 0) * 1024;
        float* dst1 = slab + ((pair * 2 + (1 - half)) * 2 + 1) * 1024;
        if (half == 0) {
            DUMP_ACC(Oacc[2], dst0);
            DUMP_ACC(Oacc[3], dst1);
        } else {
            DUMP_ACC(Oacc[0], dst0);
            DUMP_ACC(Oacc[1], dst1);
        }
    }
    __syncthreads();

    // per-thread block-partial denominators (this khalf only)
    float psB[16];
#pragma unroll
    for (int rq = 0; rq < 4; ++rq)
#pragma unroll
        for (int r = 0; r < 4; ++r) {
            const int ql = r + 8 * rq + 4 * hi;
            psB[rq * 4 + r] = Lsum[pair * 2][ql] + Lsum[pair * 2 + 1][ql];
        }

    float* obase = Og + ((size_t)b * Qn + q0 + pair * 32) * DVn;
    const float* src0 = slab + ((pair * 2 + half) * 2 + 0) * 1024;
    const float* src1 = slab + ((pair * 2 + half) * 2 + 1) * 1024;

    // ---- arrival-order merge with partner khalf block ----
    if (tid == 0) roleSh = atomicAdd(&flagA[fid], 1);
    __syncthreads();
    if (roleSh == 0) {
        // first-arriver: stage raw (unnormalized) partial in Og + psums in ws
        if (half == 0) {
            STORE_RAW(Oacc[0], src0, 0);
            STORE_RAW(Oacc[1], src1, 32);
        } else {
            STORE_RAW(Oacc[2], src0, 64);
            STORE_RAW(Oacc[3], src1, 96);
        }
        if (l31 == 0 && half == 0) {
#pragma unroll
            for (int reg = 0; reg < 16; ++reg) {
                const int ql = (reg & 3) + 8 * (reg >> 2) + 4 * hi;
                psums[fid * 64 + pair * 32 + ql] = psB[reg];
            }
        }
        __threadfence();
        __syncthreads();
        if (tid == 0) atomicExch(&flagB[fid], 1);
    } else {
        // second-arriver: partner already passed flagA -> spin is bounded
        if (tid == 0) {
            while (atomicAdd(&flagB[fid], 0) == 0) __builtin_amdgcn_s_sleep(2);
        }
        __syncthreads();
        __threadfence();
        float invl[16];
#pragma unroll
        for (int reg = 0; reg < 16; ++reg) {
            const int ql = (reg & 3) + 8 * (reg >> 2) + 4 * hi;
            invl[reg] = 1.f / (psB[reg] + psums[fid * 64 + pair * 32 + ql]);
        }
        if (half == 0) {
            STORE_MRG(Oacc[0], src0, 0);
            STORE_MRG(Oacc[1], src1, 32);
        } else {
            STORE_MRG(Oacc[2], src0, 64);
            STORE_MRG(Oacc[3], src1, 96);
        }
    }
}

extern "C" void kernel_launch(void* const* d_in, const int* in_sizes, int n_in,
                              void* d_out, int out_size, void* d_ws, size_t ws_size,
                              hipStream_t stream) {
    const float* Qg = (const float*)d_in[0];
    const float* Kg = (const float*)d_in[1];
    const float* Vg = (const float*)d_in[2];
    const int*   VL = (const int*)d_in[3];
    float* Og = (float*)d_out;
    (void)ws_size;

    // ws: Kb bf16 (8MB) | Vtb bf16 (8MB) | bias f32 (128KB) | psums f32 (128KB)
    //     | flags int (4KB)
    char* ws = (char*)d_ws;
    short* Kb    = (short*)(ws);
    short* Vtb   = (short*)(ws + (size_t)Bn * Kn * Dn * 2);
    float* bias  = (float*)(ws + (size_t)Bn * Kn * Dn * 4);
    float* psums = (float*)(ws + (size_t)Bn * Kn * Dn * 4 + 131072);
    int*   flags = (int*)  (ws + (size_t)Bn * Kn * Dn * 4 + 262144);

    prep_kv<<<dim3(1024), dim3(256), 0, stream>>>(Kg, Vg, Kb, Vtb, bias, flags);
    attn_kernel<<<dim3(1024), dim3(256), 0, stream>>>(Qg, Kb, Vtb, bias, VL, Og,
                                                      psums, flags);
}

// Round 3
// 149.014 us; speedup vs baseline: 2.4692x; 2.4692x over previous
//
#include <hip/hip_runtime.h>

// B=16, Q=2048, K=2048, D=128, DV=128
// out[b,q,:] = softmax_k((q.k - 0.5||k||^2)/sqrt(192), mask k>=valid_len) @ V
// R11 = attn reverted to R8 exactly (known 65us; R10's split-K spilled regs:
// VGPR 84+AGPR at the 170-reg cap -> 83MB of scratch FETCH, 4.4x regression).
// prep_kv rewritten for coalescing: dur_us - attn_dur has been a constant
// ~83-86us across R8/R9/R10 -> prep (uncoalesced 128B-stride 16B loads) is
// the biggest remaining lever.
//  - K path: flat coalesced float4->bf16x4, row ssq via 5x shfl_xor in the
//    32-lane row group. 1024 blocks x 32 rows.
//  - V path: phase-1 coalesced row reads + XOR-swizzled LDS writes
//    (v ^ ((k&15)<<3)); phase-2 same output layout as R8 (plain V^T bf16).

#define Bn   16
#define Qn   2048
#define Kn   2048
#define Dn   128
#define DVn  128
#define BQ   64
#define BK   64

// (1/sqrt(192)) * log2(e) : softmax computed as 2^(qk*SC2 + bias2)
#define SC2 0.10411754f

typedef short bf16x4 __attribute__((ext_vector_type(4)));
typedef short bf16x8 __attribute__((ext_vector_type(8)));
typedef float f32x16 __attribute__((ext_vector_type(16)));

__device__ __forceinline__ short f2bf(float x) {   // RNE
    union { float f; unsigned u; } v; v.f = x;
    unsigned r = (v.u + 0x7fffu + ((v.u >> 16) & 1u)) >> 16;
    return (short)r;
}

typedef const __attribute__((address_space(1))) void* gas_t;
typedef __attribute__((address_space(3))) void* las_t;
__device__ __forceinline__ void gld16(const void* g, void* l) {
    __builtin_amdgcn_global_load_lds((gas_t)g, (las_t)l, 16, 0, 0);
}
__device__ __forceinline__ void gld4(const void* g, void* l) {
    __builtin_amdgcn_global_load_lds((gas_t)g, (las_t)l, 4, 0, 0);
}
__device__ __forceinline__ float exp2_raw(float a) {  // D = 2^S0
    float p;
    asm("v_exp_f32 %0, %1" : "=v"(p) : "v"(a));
    return p;
}

// ---------- preprocess (R11: coalesced) ----------
__global__ __launch_bounds__(256) void prep_kv(const float* __restrict__ Kg,
                                               const float* __restrict__ Vg,
                                               short* __restrict__ Kb,
                                               short* __restrict__ Vtb,
                                               float* __restrict__ biasg) {
    const int tid = threadIdx.x;
    if (blockIdx.x < 1024) {
        // ---- K path: 32 rows (b*Kn+row flat) per block, fully coalesced ----
        const int rowbase = blockIdx.x * 32;
        const float* src = Kg + (size_t)rowbase * Dn;
        short*       dst = Kb + (size_t)rowbase * Dn;
#pragma unroll
        for (int p = 0; p < 4; ++p) {
            const int idx = p * 1024 + tid * 4;     // flat float index
            float4 x = *(const float4*)(src + idx);
            bf16x4 h;
            h[0] = f2bf(x.x); h[1] = f2bf(x.y); h[2] = f2bf(x.z); h[3] = f2bf(x.w);
            *(bf16x4*)(dst + idx) = h;
            float ssq = x.x*x.x + x.y*x.y + x.z*x.z + x.w*x.w;
            ssq += __shfl_xor(ssq, 1);
            ssq += __shfl_xor(ssq, 2);
            ssq += __shfl_xor(ssq, 4);
            ssq += __shfl_xor(ssq, 8);
            ssq += __shfl_xor(ssq, 16);
            if ((tid & 31) == 0)
                biasg[rowbase + p * 8 + (tid >> 5)] = -0.5f * ssq * SC2;
        }
    } else {
        // ---- V path: transpose one [64 k][128 v] tile to plain V^T bf16 ----
        const int blk = blockIdx.x - 1024;
        const int b  = blk >> 5;
        const int k0 = (blk & 31) * 64;
        __shared__ short Ls[64 * 128];
        // phase 1: coalesced float4 row reads; XOR-swizzled LDS writes
#pragma unroll
        for (int p = 0; p < 8; ++p) {
            const int kk = p * 8 + (tid >> 5);      // tile row 0..63
            const int v0 = (tid & 31) * 4;
            float4 x = *(const float4*)(Vg + ((size_t)b * Kn + k0 + kk) * DVn + v0);
            bf16x4 h;
            h[0] = f2bf(x.x); h[1] = f2bf(x.y); h[2] = f2bf(x.z); h[3] = f2bf(x.w);
            const int vs = v0 ^ ((kk & 15) << 3);   // keeps 4-short alignment
            *(bf16x4*)&Ls[kk * 128 + vs] = h;
        }
        __syncthreads();
        // phase 2: column gather (32 scalar reads) + coalesced 64B stores
        const int v = tid >> 1;
        const int h = (tid & 1) * 32;
        short* dst = Vtb + ((size_t)b * DVn + v) * Kn + k0 + h;
#pragma unroll
        for (int j4 = 0; j4 < 4; ++j4) {
            bf16x8 o;
#pragma unroll
            for (int j = 0; j < 8; ++j) {
                const int kk = h + j4 * 8 + j;
                o[j] = Ls[kk * 128 + (v ^ ((kk & 15) << 3))];
            }
            *(bf16x8*)(dst + j4 * 8) = o;
        }
    }
}

// epilogue helpers with LITERAL accumulator indices (no runtime Oacc[] index)
#define DUMP_ACC(ACC, DST)                                            \
    {                                                                 \
        _Pragma("unroll")                                             \
        for (int reg = 0; reg < 16; ++reg) {                          \
            const int row = (reg & 3) + 8 * (reg >> 2) + 4 * hi;      \
            (DST)[row * 32 + l31] = (ACC)[reg];                       \
        }                                                             \
    }
#define STORE_ACC(ACC, SRC, COLBASE)                                  \
    {                                                                 \
        _Pragma("unroll")                                             \
        for (int reg = 0; reg < 16; ++reg) {                          \
            const int row = (reg & 3) + 8 * (reg >> 2) + 4 * hi;      \
            const float o = (ACC)[reg] + (SRC)[row * 32 + l31];       \
            obase[(size_t)row * DVn + (COLBASE) + l31] = o * invl[reg]; \
        }                                                             \
    }

// ---------- main attention kernel (R8 verbatim) ----------
__global__ __launch_bounds__(256, 2) void attn_kernel(
    const float* __restrict__ Qg, const short* __restrict__ Kb,
    const short* __restrict__ Vtb, const float* __restrict__ biasg,
    const int* __restrict__ VL, float* __restrict__ Og)
{
    // K tile: 64 rows x 256B, chunk XOR by (row&15)
    // V tile: 64 rows x 256B; row r holds v=2r (slots c<8) and v=2r+1 (c>=8),
    //         slot position p = c ^ (r&15)
    __shared__ __align__(16) short Ksh[2][64 * 128];   // 32768 B (epilogue: float slab)
    __shared__ __align__(16) short Vsh[2][64 * 128];   // 32768 B
    __shared__ __align__(16) float biasSh[2][64];      //   512 B
    __shared__ float Lsum[4][32];                      //   512 B -> 66560 B total

    const int tid  = threadIdx.x;
    const int lane = tid & 63;
    const int w    = tid >> 6;    // wave 0..3
    const int pair = w >> 1;      // q-strip: rows [pair*32, pair*32+32)
    const int half = w & 1;       // key-half (S and PV k-range), wave-uniform
    const int l31  = lane & 31;
    const int hi   = lane >> 5;

    const int lin  = blockIdx.x;          // 0..511 ; XCD swizzle
    const int slot = lin >> 3;
    const int b    = (lin & 7) * 2 + (slot >> 5);
    const int q0   = (slot & 31) * BQ;

    const short* Kb_b = Kb  + (size_t)b * Kn * Dn;
    const short* Vt_b = Vtb + (size_t)b * DVn * Kn;
    const float* bias_b = biasg + b * Kn;

    // ---- DMA source pointers ----
    const short* ksp[4]; int kdo[4];
    const short* vsp[4]; int vdo[4];
#pragma unroll
    for (int i = 0; i < 4; ++i) {
        const int rl = w * 16 + i * 4 + (lane >> 4);       // K tile row 0..63
        const int ch = (lane & 15) ^ (rl & 15);
        ksp[i] = Kb_b + (size_t)rl * Dn + ch * 8;
        kdo[i] = (w * 16 + i * 4) * 128;
        const int rv = w * 16 + i * 4 + (lane >> 4);       // V tile row 0..63
        const int cc = (lane & 15) ^ (rv & 15);            // source chunk
        const int vv = 2 * rv + (cc >> 3);
        vsp[i] = Vt_b + (size_t)vv * Kn + (cc & 7) * 8;
        vdo[i] = (w * 16 + i * 4) * 128;
    }

    // ---- Q fragments: frag layout [n=l31][k=kt*16+hi*8+j] ----
    bf16x8 qf[8];
    {
        const float* qrow = Qg + ((size_t)b * Qn + q0 + pair * 32 + l31) * Dn;
#pragma unroll
        for (int kt = 0; kt < 8; ++kt) {
            const float* p = qrow + kt * 16 + hi * 8;
            float4 x0 = *(const float4*)(p);
            float4 x1 = *(const float4*)(p + 4);
            bf16x8 f;
            f[0]=f2bf(x0.x); f[1]=f2bf(x0.y); f[2]=f2bf(x0.z); f[3]=f2bf(x0.w);
            f[4]=f2bf(x1.x); f[5]=f2bf(x1.y); f[6]=f2bf(x1.z); f[7]=f2bf(x1.w);
            qf[kt] = f;
        }
    }
    const int vlq = VL[b * Qn + q0 + pair * 32 + l31];

    f32x16 Oacc[4];   // v = nt*32 + l31, all 128 v; keys restricted to own half
#pragma unroll
    for (int nt = 0; nt < 4; ++nt)
#pragma unroll
        for (int j = 0; j < 16; ++j) Oacc[nt][j] = 0.f;
    float psum = 0.f;

    // prologue: DMA tile 0 into buffer 0
#pragma unroll
    for (int i = 0; i < 4; ++i) {
        gld16(ksp[i], &Ksh[0][kdo[i]]);
        gld16(vsp[i], &Vsh[0][vdo[i]]);
    }
    if (w == 0) gld4(bias_b + lane, &biasSh[0][0]);

    for (int k0k = 0; k0k < Kn; k0k += BK) {
        const int buf = (k0k >> 6) & 1;
        __syncthreads();   // drains vmcnt(0): tile ready; prev readers done

        if (k0k + BK < Kn) {
            const int nk = k0k + BK;
#pragma unroll
            for (int i = 0; i < 4; ++i) {
                gld16(ksp[i] + (size_t)nk * Dn, &Ksh[buf ^ 1][kdo[i]]);
                gld16(vsp[i] + nk,              &Vsh[buf ^ 1][vdo[i]]);
            }
            if (w == 0) gld4(bias_b + nk + lane, &biasSh[buf ^ 1][0]);
        }

        float4 bv[4];
#pragma unroll
        for (int rq = 0; rq < 4; ++rq)
            bv[rq] = *(const float4*)&biasSh[buf][half * 32 + rq * 8 + hi * 4];

        // ---- S^T = K_half . Q^T : one 32x32 tile per wave (8 MFMA) ----
        const short* kbuf = Ksh[buf];
        const int kr = half * 32 + l31;
        f32x16 Sv;
#pragma unroll
        for (int j = 0; j < 16; ++j) Sv[j] = 0.f;
#pragma unroll
        for (int kt = 0; kt < 8; ++kt) {
            bf16x8 kf = *(const bf16x8*)&kbuf[kr * 128 + (((kt*2 + hi) ^ (kr & 15)) * 8)];
            Sv = __builtin_amdgcn_mfma_f32_32x32x16_bf16(kf, qf[kt], Sv, 0, 0, 0);
        }

        // ---- softmax in exp2 domain (results back into Sv) ----
#pragma unroll
        for (int rq = 0; rq < 4; ++rq) {
#pragma unroll
            for (int r = 0; r < 4; ++r) {
                const int reg = rq * 4 + r;
                const int keyg = k0k + half * 32 + rq * 8 + hi * 4 + r;
                float a = fmaf(Sv[reg], SC2, bv[rq][r]);
                a = (keyg < vlq) ? a : -200.0f;
                const float p = exp2_raw(a);
                psum += p;
                Sv[reg] = p;
            }
        }

        // ---- PV: C-layout -> A-layout via lane^32 exchange; 8 MFMA ----
        const short* vbuf = Vsh[buf];
#pragma unroll
        for (int kt = 0; kt < 2; ++kt) {
            unsigned kAx = __builtin_amdgcn_perm(__float_as_uint(Sv[(2*kt)*4+1]),
                                                 __float_as_uint(Sv[(2*kt)*4+0]), 0x07060302u);
            unsigned kAy = __builtin_amdgcn_perm(__float_as_uint(Sv[(2*kt)*4+3]),
                                                 __float_as_uint(Sv[(2*kt)*4+2]), 0x07060302u);
            unsigned kBx = __builtin_amdgcn_perm(__float_as_uint(Sv[(2*kt+1)*4+1]),
                                                 __float_as_uint(Sv[(2*kt+1)*4+0]), 0x07060302u);
            unsigned kBy = __builtin_amdgcn_perm(__float_as_uint(Sv[(2*kt+1)*4+3]),
                                                 __float_as_uint(Sv[(2*kt+1)*4+2]), 0x07060302u);
            const unsigned sx = hi ? kAx : kBx;
            const unsigned sy = hi ? kAy : kBy;
            const unsigned rx = __shfl_xor(sx, 32);
            const unsigned ry = __shfl_xor(sy, 32);
            uint4 au;
            au.x = hi ? rx : kAx;
            au.y = hi ? ry : kAy;
            au.z = hi ? kBx : rx;
            au.w = hi ? kBy : ry;
            const bf16x8 af = __builtin_bit_cast(bf16x8, au);
            const int kc = half * 4 + kt * 2 + hi;   // key-chunk within 64-key tile
#pragma unroll
            for (int nt = 0; nt < 4; ++nt) {
                const int v  = nt * 32 + l31;
                const int r  = v >> 1;
                const int p  = ((v & 1) * 8 + kc) ^ (r & 15);
                bf16x8 vf = *(const bf16x8*)&vbuf[r * 128 + p * 8];
                Oacc[nt] = __builtin_amdgcn_mfma_f32_32x32x16_bf16(af, vf, Oacc[nt], 0, 0, 0);
            }
        }
    }

    // ---- epilogue: combine key-halves across wave pairs via LDS ----
    psum += __shfl_xor(psum, 32);
    if (lane < 32) Lsum[w][l31] = psum;
    __syncthreads();   // all waves done reading Ksh/Vsh -> safe to reuse Ksh

    float* slab = (float*)&Ksh[0][0];
    // write the half the PARTNER will store (literal Oacc indices; half is
    // wave-uniform so this is a scalar branch, not divergence)
    {
        float* dst0 = slab + ((pair * 2 + (1 - half)) * 2 + 0) * 1024;
        float* dst1 = slab + ((pair * 2 + (1 - half)) * 2 + 1) * 1024;
        if (half == 0) {
            DUMP_ACC(Oacc[2], dst0);
            DUMP_ACC(Oacc[3], dst1);
        } else {
            DUMP_ACC(Oacc[0], dst0);
            DUMP_ACC(Oacc[1], dst1);
        }
    }
    __syncthreads();

    float invl[16];
#pragma unroll
    for (int rq = 0; rq < 4; ++rq)
#pragma unroll
        for (int r = 0; r < 4; ++r) {
            const int ql = r + 8 * rq + 4 * hi;
            invl[rq*4+r] = 1.f / (Lsum[pair*2][ql] + Lsum[pair*2+1][ql]);
        }
    float* obase = Og + ((size_t)b * Qn + q0 + pair * 32) * DVn;
    {
        const float* src0 = slab + ((pair * 2 + half) * 2 + 0) * 1024;
        const float* src1 = slab + ((pair * 2 + half) * 2 + 1) * 1024;
        if (half == 0) {
            STORE_ACC(Oacc[0], src0, 0);
            STORE_ACC(Oacc[1], src1, 32);
        } else {
            STORE_ACC(Oacc[2], src0, 64);
            STORE_ACC(Oacc[3], src1, 96);
        }
    }
}

extern "C" void kernel_launch(void* const* d_in, const int* in_sizes, int n_in,
                              void* d_out, int out_size, void* d_ws, size_t ws_size,
                              hipStream_t stream) {
    const float* Qg = (const float*)d_in[0];
    const float* Kg = (const float*)d_in[1];
    const float* Vg = (const float*)d_in[2];
    const int*   VL = (const int*)d_in[3];
    float* Og = (float*)d_out;

    // ws: Kb bf16 (8MB) | Vtb bf16 (8MB) | bias2 f32 (128KB)
    char* ws = (char*)d_ws;
    short* Kb   = (short*)(ws);
    short* Vtb  = (short*)(ws + (size_t)Bn * Kn * Dn * 2);
    float* bias = (float*)(ws + (size_t)Bn * Kn * Dn * 4);

    prep_kv<<<dim3(1536), dim3(256), 0, stream>>>(Kg, Vg, Kb, Vtb, bias);
    attn_kernel<<<dim3(512), dim3(256), 0, stream>>>(Qg, Kb, Vtb, bias, VL, Og);
}

// Round 4
// 147.890 us; speedup vs baseline: 2.4879x; 1.0076x over previous
//
#include <hip/hip_runtime.h>

// B=16, Q=2048, K=2048, D=128, DV=128
// out[b,q,:] = softmax_k((q.k - 0.5||k||^2)/sqrt(192), mask k>=valid_len) @ V
// R12 = R11 prep + counted-vmcnt attn pipeline (T3/T4):
//  - raw s_barrier + "s_waitcnt vmcnt(9)" replaces __syncthreads(): tile i+1's
//    9 DMA loads stay IN FLIGHT across the barrier (never drain to 0 in-loop).
//  - all fragments (K 8x b128, V 8x b128, bias 4x b128) pre-read to registers,
//    lgkmcnt(0)+barrier releases the buffer, tile i+2 issued immediately ->
//    every DMA gets a full iteration of compute to land under.
//  - bias gld4 issued by ALL waves (uniform 9 vmem ops/iter/wave, required
//    for counted vmcnt; redundant identical 256B DMA writes are benign).
// Register budget: ~220 unified (cap 256 @ 2 blocks/CU). If FETCH_SIZE
// balloons vs 16.6MB -> spill -> revert.

#define Bn   16
#define Qn   2048
#define Kn   2048
#define Dn   128
#define DVn  128
#define BQ   64
#define BK   64

// (1/sqrt(192)) * log2(e) : softmax computed as 2^(qk*SC2 + bias2)
#define SC2 0.10411754f

typedef short bf16x4 __attribute__((ext_vector_type(4)));
typedef short bf16x8 __attribute__((ext_vector_type(8)));
typedef float f32x16 __attribute__((ext_vector_type(16)));

__device__ __forceinline__ short f2bf(float x) {   // RNE
    union { float f; unsigned u; } v; v.f = x;
    unsigned r = (v.u + 0x7fffu + ((v.u >> 16) & 1u)) >> 16;
    return (short)r;
}

typedef const __attribute__((address_space(1))) void* gas_t;
typedef __attribute__((address_space(3))) void* las_t;
__device__ __forceinline__ void gld16(const void* g, void* l) {
    __builtin_amdgcn_global_load_lds((gas_t)g, (las_t)l, 16, 0, 0);
}
__device__ __forceinline__ void gld4(const void* g, void* l) {
    __builtin_amdgcn_global_load_lds((gas_t)g, (las_t)l, 4, 0, 0);
}
__device__ __forceinline__ float exp2_raw(float a) {  // D = 2^S0
    float p;
    asm("v_exp_f32 %0, %1" : "=v"(p) : "v"(a));
    return p;
}

// compiler-level memory fences + HW waits (counted: loads stay in flight)
#define VMW9() asm volatile("s_waitcnt vmcnt(9)" ::: "memory")
#define VMW0() asm volatile("s_waitcnt vmcnt(0)" ::: "memory")
#define LGW()  asm volatile("s_waitcnt lgkmcnt(0)" ::: "memory")

// ---------- preprocess (R11: coalesced) ----------
__global__ __launch_bounds__(256) void prep_kv(const float* __restrict__ Kg,
                                               const float* __restrict__ Vg,
                                               short* __restrict__ Kb,
                                               short* __restrict__ Vtb,
                                               float* __restrict__ biasg) {
    const int tid = threadIdx.x;
    if (blockIdx.x < 1024) {
        // ---- K path: 32 rows (b*Kn+row flat) per block, fully coalesced ----
        const int rowbase = blockIdx.x * 32;
        const float* src = Kg + (size_t)rowbase * Dn;
        short*       dst = Kb + (size_t)rowbase * Dn;
#pragma unroll
        for (int p = 0; p < 4; ++p) {
            const int idx = p * 1024 + tid * 4;     // flat float index
            float4 x = *(const float4*)(src + idx);
            bf16x4 h;
            h[0] = f2bf(x.x); h[1] = f2bf(x.y); h[2] = f2bf(x.z); h[3] = f2bf(x.w);
            *(bf16x4*)(dst + idx) = h;
            float ssq = x.x*x.x + x.y*x.y + x.z*x.z + x.w*x.w;
            ssq += __shfl_xor(ssq, 1);
            ssq += __shfl_xor(ssq, 2);
            ssq += __shfl_xor(ssq, 4);
            ssq += __shfl_xor(ssq, 8);
            ssq += __shfl_xor(ssq, 16);
            if ((tid & 31) == 0)
                biasg[rowbase + p * 8 + (tid >> 5)] = -0.5f * ssq * SC2;
        }
    } else {
        // ---- V path: transpose one [64 k][128 v] tile to plain V^T bf16 ----
        const int blk = blockIdx.x - 1024;
        const int b  = blk >> 5;
        const int k0 = (blk & 31) * 64;
        __shared__ short Ls[64 * 128];
        // phase 1: coalesced float4 row reads; XOR-swizzled LDS writes
#pragma unroll
        for (int p = 0; p < 8; ++p) {
            const int kk = p * 8 + (tid >> 5);      // tile row 0..63
            const int v0 = (tid & 31) * 4;
            float4 x = *(const float4*)(Vg + ((size_t)b * Kn + k0 + kk) * DVn + v0);
            bf16x4 h;
            h[0] = f2bf(x.x); h[1] = f2bf(x.y); h[2] = f2bf(x.z); h[3] = f2bf(x.w);
            const int vs = v0 ^ ((kk & 15) << 3);   // keeps 4-short alignment
            *(bf16x4*)&Ls[kk * 128 + vs] = h;
        }
        __syncthreads();
        // phase 2: column gather (32 scalar reads) + coalesced 64B stores
        const int v = tid >> 1;
        const int h = (tid & 1) * 32;
        short* dst = Vtb + ((size_t)b * DVn + v) * Kn + k0 + h;
#pragma unroll
        for (int j4 = 0; j4 < 4; ++j4) {
            bf16x8 o;
#pragma unroll
            for (int j = 0; j < 8; ++j) {
                const int kk = h + j4 * 8 + j;
                o[j] = Ls[kk * 128 + (v ^ ((kk & 15) << 3))];
            }
            *(bf16x8*)(dst + j4 * 8) = o;
        }
    }
}

// epilogue helpers with LITERAL accumulator indices (no runtime Oacc[] index)
#define DUMP_ACC(ACC, DST)                                            \
    {                                                                 \
        _Pragma("unroll")                                             \
        for (int reg = 0; reg < 16; ++reg) {                          \
            const int row = (reg & 3) + 8 * (reg >> 2) + 4 * hi;      \
            (DST)[row * 32 + l31] = (ACC)[reg];                       \
        }                                                             \
    }
#define STORE_ACC(ACC, SRC, COLBASE)                                  \
    {                                                                 \
        _Pragma("unroll")                                             \
        for (int reg = 0; reg < 16; ++reg) {                          \
            const int row = (reg & 3) + 8 * (reg >> 2) + 4 * hi;      \
            const float o = (ACC)[reg] + (SRC)[row * 32 + l31];       \
            obase[(size_t)row * DVn + (COLBASE) + l31] = o * invl[reg]; \
        }                                                             \
    }

// ---- R12 loop building blocks (all register indices literal) ----

// read ALL of tile I's fragments from LDS into registers
#define FRAG_LOADS(I)                                                      \
    {                                                                      \
        const short* kbuf = Ksh[(I) & 1];                                  \
        const short* vbuf = Vsh[(I) & 1];                                  \
        _Pragma("unroll")                                                  \
        for (int kt = 0; kt < 8; ++kt)                                     \
            kf[kt] = *(const bf16x8*)&kbuf[kr * 128 + (((kt*2 + hi) ^ (kr & 15)) * 8)]; \
        _Pragma("unroll")                                                  \
        for (int kt = 0; kt < 2; ++kt) {                                   \
            const int kc = half * 4 + kt * 2 + hi;                         \
            _Pragma("unroll")                                              \
            for (int nt = 0; nt < 4; ++nt) {                               \
                const int v  = nt * 32 + l31;                              \
                const int r  = v >> 1;                                     \
                const int p  = ((v & 1) * 8 + kc) ^ (r & 15);              \
                vfr[kt][nt] = *(const bf16x8*)&vbuf[r * 128 + p * 8];      \
            }                                                              \
        }                                                                  \
        _Pragma("unroll")                                                  \
        for (int rq = 0; rq < 4; ++rq)                                     \
            bv[rq] = *(const float4*)&biasSh[(I) & 1][half * 32 + rq * 8 + hi * 4]; \
    }

// issue tile T's 9 DMA loads (4 K + 4 V + 1 bias) into buffer T&1
#define STAGE(T)                                                           \
    {                                                                      \
        const int nk = (T) * BK;                                           \
        _Pragma("unroll")                                                  \
        for (int u = 0; u < 4; ++u) {                                      \
            gld16(ksp[u] + (size_t)nk * Dn, &Ksh[(T) & 1][kdo[u]]);        \
            gld16(vsp[u] + nk,              &Vsh[(T) & 1][vdo[u]]);        \
        }                                                                  \
        gld4(bias_b + nk + lane, &biasSh[(T) & 1][0]);                     \
    }

// S + softmax + PV for tile I, everything already in registers
#define COMPUTE(I)                                                         \
    {                                                                      \
        f32x16 Sv;                                                         \
        _Pragma("unroll")                                                  \
        for (int j = 0; j < 16; ++j) Sv[j] = 0.f;                          \
        __builtin_amdgcn_s_setprio(1);                                     \
        _Pragma("unroll")                                                  \
        for (int kt = 0; kt < 8; ++kt)                                     \
            Sv = __builtin_amdgcn_mfma_f32_32x32x16_bf16(kf[kt], qf[kt], Sv, 0, 0, 0); \
        __builtin_amdgcn_s_setprio(0);                                     \
        _Pragma("unroll")                                                  \
        for (int rq = 0; rq < 4; ++rq) {                                   \
            _Pragma("unroll")                                              \
            for (int r = 0; r < 4; ++r) {                                  \
                const int reg = rq * 4 + r;                                \
                const int keyg = (I) * BK + half * 32 + rq * 8 + hi * 4 + r; \
                float a = fmaf(Sv[reg], SC2, bv[rq][r]);                   \
                a = (keyg < vlq) ? a : -200.0f;                            \
                const float p = exp2_raw(a);                               \
                psum += p;                                                 \
                Sv[reg] = p;                                               \
            }                                                              \
        }                                                                  \
        _Pragma("unroll")                                                  \
        for (int kt = 0; kt < 2; ++kt) {                                   \
            unsigned kAx = __builtin_amdgcn_perm(__float_as_uint(Sv[(2*kt)*4+1]),   \
                                                 __float_as_uint(Sv[(2*kt)*4+0]), 0x07060302u); \
            unsigned kAy = __builtin_amdgcn_perm(__float_as_uint(Sv[(2*kt)*4+3]),   \
                                                 __float_as_uint(Sv[(2*kt)*4+2]), 0x07060302u); \
            unsigned kBx = __builtin_amdgcn_perm(__float_as_uint(Sv[(2*kt+1)*4+1]), \
                                                 __float_as_uint(Sv[(2*kt+1)*4+0]), 0x07060302u); \
            unsigned kBy = __builtin_amdgcn_perm(__float_as_uint(Sv[(2*kt+1)*4+3]), \
                                                 __float_as_uint(Sv[(2*kt+1)*4+2]), 0x07060302u); \
            const unsigned sx = hi ? kAx : kBx;                            \
            const unsigned sy = hi ? kAy : kBy;                            \
            const unsigned rx = __shfl_xor(sx, 32);                        \
            const unsigned ry = __shfl_xor(sy, 32);                        \
            uint4 au;                                                      \
            au.x = hi ? rx : kAx;                                          \
            au.y = hi ? ry : kAy;                                          \
            au.z = hi ? kBx : rx;                                          \
            au.w = hi ? kBy : ry;                                          \
            const bf16x8 af = __builtin_bit_cast(bf16x8, au);              \
            __builtin_amdgcn_s_setprio(1);                                 \
            Oacc[0] = __builtin_amdgcn_mfma_f32_32x32x16_bf16(af, vfr[kt][0], Oacc[0], 0, 0, 0); \
            Oacc[1] = __builtin_amdgcn_mfma_f32_32x32x16_bf16(af, vfr[kt][1], Oacc[1], 0, 0, 0); \
            Oacc[2] = __builtin_amdgcn_mfma_f32_32x32x16_bf16(af, vfr[kt][2], Oacc[2], 0, 0, 0); \
            Oacc[3] = __builtin_amdgcn_mfma_f32_32x32x16_bf16(af, vfr[kt][3], Oacc[3], 0, 0, 0); \
            __builtin_amdgcn_s_setprio(0);                                 \
        }                                                                  \
    }

// ---------- main attention kernel ----------
__global__ __launch_bounds__(256, 2) void attn_kernel(
    const float* __restrict__ Qg, const short* __restrict__ Kb,
    const short* __restrict__ Vtb, const float* __restrict__ biasg,
    const int* __restrict__ VL, float* __restrict__ Og)
{
    // K tile: 64 rows x 256B, chunk XOR by (row&15)
    // V tile: 64 rows x 256B; row r holds v=2r (slots c<8) and v=2r+1 (c>=8),
    //         slot position p = c ^ (r&15)
    __shared__ __align__(16) short Ksh[2][64 * 128];   // 32768 B (epilogue: float slab)
    __shared__ __align__(16) short Vsh[2][64 * 128];   // 32768 B
    __shared__ __align__(16) float biasSh[2][64];      //   512 B
    __shared__ float Lsum[4][32];                      //   512 B -> 66560 B total

    const int tid  = threadIdx.x;
    const int lane = tid & 63;
    const int w    = tid >> 6;    // wave 0..3
    const int pair = w >> 1;      // q-strip: rows [pair*32, pair*32+32)
    const int half = w & 1;       // key-half (S and PV k-range), wave-uniform
    const int l31  = lane & 31;
    const int hi   = lane >> 5;

    const int lin  = blockIdx.x;          // 0..511 ; XCD swizzle
    const int slot = lin >> 3;
    const int b    = (lin & 7) * 2 + (slot >> 5);
    const int q0   = (slot & 31) * BQ;

    const short* Kb_b = Kb  + (size_t)b * Kn * Dn;
    const short* Vt_b = Vtb + (size_t)b * DVn * Kn;
    const float* bias_b = biasg + b * Kn;

    // ---- DMA source pointers ----
    const short* ksp[4]; int kdo[4];
    const short* vsp[4]; int vdo[4];
#pragma unroll
    for (int i = 0; i < 4; ++i) {
        const int rl = w * 16 + i * 4 + (lane >> 4);       // K tile row 0..63
        const int ch = (lane & 15) ^ (rl & 15);
        ksp[i] = Kb_b + (size_t)rl * Dn + ch * 8;
        kdo[i] = (w * 16 + i * 4) * 128;
        const int rv = w * 16 + i * 4 + (lane >> 4);       // V tile row 0..63
        const int cc = (lane & 15) ^ (rv & 15);            // source chunk
        const int vv = 2 * rv + (cc >> 3);
        vsp[i] = Vt_b + (size_t)vv * Kn + (cc & 7) * 8;
        vdo[i] = (w * 16 + i * 4) * 128;
    }

    // ---- Q fragments: frag layout [n=l31][k=kt*16+hi*8+j] ----
    bf16x8 qf[8];
    {
        const float* qrow = Qg + ((size_t)b * Qn + q0 + pair * 32 + l31) * Dn;
#pragma unroll
        for (int kt = 0; kt < 8; ++kt) {
            const float* p = qrow + kt * 16 + hi * 8;
            float4 x0 = *(const float4*)(p);
            float4 x1 = *(const float4*)(p + 4);
            bf16x8 f;
            f[0]=f2bf(x0.x); f[1]=f2bf(x0.y); f[2]=f2bf(x0.z); f[3]=f2bf(x0.w);
            f[4]=f2bf(x1.x); f[5]=f2bf(x1.y); f[6]=f2bf(x1.z); f[7]=f2bf(x1.w);
            qf[kt] = f;
        }
    }
    const int vlq = VL[b * Qn + q0 + pair * 32 + l31];
    const int kr  = half * 32 + l31;     // K row this lane reads for S

    f32x16 Oacc[4];   // v = nt*32 + l31, all 128 v; keys restricted to own half
#pragma unroll
    for (int nt = 0; nt < 4; ++nt)
#pragma unroll
        for (int j = 0; j < 16; ++j) Oacc[nt][j] = 0.f;
    float psum = 0.f;

    bf16x8 kf[8];          // K fragments of current tile
    bf16x8 vfr[2][4];      // V fragments of current tile
    float4 bv[4];          // bias of current tile

    // prologue: issue tiles 0 and 1 (9 loads each; both buffers)
    STAGE(0);
    STAGE(1);

    // main loop: iters 0..29 stage tile I+2; 30/31 drain.
#pragma unroll 1
    for (int I = 0; I < 30; ++I) {
        VMW9();                              // tile I's 9 loads done (I+1 in flight)
        __builtin_amdgcn_s_barrier();        // ..for ALL waves
        FRAG_LOADS(I);
        LGW();                               // frags in regs
        __builtin_amdgcn_s_barrier();        // all waves released buffer I&1
        STAGE(I + 2);                        // overwrite it; lands under compute
        COMPUTE(I);
    }
    // I=30: no stage (tile 32 doesn't exist) -> no release barrier needed
    VMW9();
    __builtin_amdgcn_s_barrier();
    FRAG_LOADS(30);
    COMPUTE(30);
    // I=31: last tile; drain everything
    VMW0();
    __builtin_amdgcn_s_barrier();
    FRAG_LOADS(31);
    COMPUTE(31);

    // ---- epilogue: combine key-halves across wave pairs via LDS ----
    psum += __shfl_xor(psum, 32);
    if (lane < 32) Lsum[w][l31] = psum;
    __syncthreads();   // all waves done reading Ksh/Vsh -> safe to reuse Ksh

    float* slab = (float*)&Ksh[0][0];
    // write the half the PARTNER will store (literal Oacc indices; half is
    // wave-uniform so this is a scalar branch, not divergence)
    {
        float* dst0 = slab + ((pair * 2 + (1 - half)) * 2 + 0) * 1024;
        float* dst1 = slab + ((pair * 2 + (1 - half)) * 2 + 1) * 1024;
        if (half == 0) {
            DUMP_ACC(Oacc[2], dst0);
            DUMP_ACC(Oacc[3], dst1);
        } else {
            DUMP_ACC(Oacc[0], dst0);
            DUMP_ACC(Oacc[1], dst1);
        }
    }
    __syncthreads();

    float invl[16];
#pragma unroll
    for (int rq = 0; rq < 4; ++rq)
#pragma unroll
        for (int r = 0; r < 4; ++r) {
            const int ql = r + 8 * rq + 4 * hi;
            invl[rq*4+r] = 1.f / (Lsum[pair*2][ql] + Lsum[pair*2+1][ql]);
        }
    float* obase = Og + ((size_t)b * Qn + q0 + pair * 32) * DVn;
    {
        const float* src0 = slab + ((pair * 2 + half) * 2 + 0) * 1024;
        const float* src1 = slab + ((pair * 2 + half) * 2 + 1) * 1024;
        if (half == 0) {
            STORE_ACC(Oacc[0], src0, 0);
            STORE_ACC(Oacc[1], src1, 32);
        } else {
            STORE_ACC(Oacc[2], src0, 64);
            STORE_ACC(Oacc[3], src1, 96);
        }
    }
}

extern "C" void kernel_launch(void* const* d_in, const int* in_sizes, int n_in,
                              void* d_out, int out_size, void* d_ws, size_t ws_size,
                              hipStream_t stream) {
    const float* Qg = (const float*)d_in[0];
    const float* Kg = (const float*)d_in[1];
    const float* Vg = (const float*)d_in[2];
    const int*   VL = (const int*)d_in[3];
    float* Og = (float*)d_out;

    // ws: Kb bf16 (8MB) | Vtb bf16 (8MB) | bias2 f32 (128KB)
    char* ws = (char*)d_ws;
    short* Kb   = (short*)(ws);
    short* Vtb  = (short*)(ws + (size_t)Bn * Kn * Dn * 2);
    float* bias = (float*)(ws + (size_t)Bn * Kn * Dn * 4);

    prep_kv<<<dim3(1536), dim3(256), 0, stream>>>(Kg, Vg, Kb, Vtb, bias);
    attn_kernel<<<dim3(512), dim3(256), 0, stream>>>(Qg, Kb, Vtb, bias, VL, Og);
}